// Round 17
// baseline (345.927 us; speedup 1.0000x reference)
//
#include <hip/hip_runtime.h>

// S,P,M=(128,2048,64), NC,NB=(16,8), H,W=512, EXTENT=12, EPS=1e-9
#define NS   128
#define NP   2048
#define NM   64
#define NCYL 16
#define NBOX 8
#define IH   512
#define IW   512
#define NPIX (IH*IW)
#define FEXT 12.0f
#define FEPS 1e-9f
#define PXSCALE ((float)IW / (2.0f * FEXT))
#define PRUNE_MARGIN 0.05f
#define SPT  8       // sources per thread
#define NTILE 256    // 16x16 grid of 32x32-pixel tiles
#define MAXSPLIT 32  // max pass-2 blocks per tile (gimg copies)
#define TARGET 2048u // target records per pass-2 block (uniform blocks)

__device__ __forceinline__ float frcp(float x)   { return __builtin_amdgcn_rcpf(x); }
__device__ __forceinline__ float frsq(float x)   { return __builtin_amdgcn_rsqf(x); }
__device__ __forceinline__ float fsqrt_(float x) { return __builtin_amdgcn_sqrtf(x); }
__device__ __forceinline__ float clamp01(float x){ return fminf(fmaxf(x, 0.0f), 1.0f); }

// ---------------- Pre-pass A: per-mirror bounding sphere of transformed points
__global__ __launch_bounds__(256) void mirror_bounds_kernel(
    const float* __restrict__ mpts, const float* __restrict__ mpos,
    const float* __restrict__ mrot, float4* __restrict__ bounds)
{
    const int m = blockIdx.x;
    const int t = threadIdx.x;
    float R0 = mrot[m*9+0], R1 = mrot[m*9+1], R2 = mrot[m*9+2];
    float R3 = mrot[m*9+3], R4 = mrot[m*9+4], R5 = mrot[m*9+5];
    float R6 = mrot[m*9+6], R7 = mrot[m*9+7], R8 = mrot[m*9+8];
    float posx = mpos[m*3+0], posy = mpos[m*3+1], posz = mpos[m*3+2];

    float mnx = 1e30f, mny = 1e30f, mnz = 1e30f;
    float mxx = -1e30f, mxy = -1e30f, mxz = -1e30f;
    for (int i = t; i < NP; i += 256) {
        long id = ((long)m * NP + i) * 3;
        float px = mpts[id+0], py = mpts[id+1], pz = mpts[id+2];
        float tx = R0*px + R1*py + R2*pz + posx;
        float ty = R3*px + R4*py + R5*pz + posy;
        float tz = R6*px + R7*py + R8*pz + posz;
        mnx = fminf(mnx, tx); mny = fminf(mny, ty); mnz = fminf(mnz, tz);
        mxx = fmaxf(mxx, tx); mxy = fmaxf(mxy, ty); mxz = fmaxf(mxz, tz);
    }
    __shared__ float red[6][256];
    red[0][t] = mnx; red[1][t] = mny; red[2][t] = mnz;
    red[3][t] = mxx; red[4][t] = mxy; red[5][t] = mxz;
    __syncthreads();
    for (int off = 128; off > 0; off >>= 1) {
        if (t < off) {
            red[0][t] = fminf(red[0][t], red[0][t+off]);
            red[1][t] = fminf(red[1][t], red[1][t+off]);
            red[2][t] = fminf(red[2][t], red[2][t+off]);
            red[3][t] = fmaxf(red[3][t], red[3][t+off]);
            red[4][t] = fmaxf(red[4][t], red[4][t+off]);
            red[5][t] = fmaxf(red[5][t], red[5][t+off]);
        }
        __syncthreads();
    }
    if (t == 0) {
        float cx = 0.5f*(red[0][0]+red[3][0]);
        float cy = 0.5f*(red[1][0]+red[4][0]);
        float cz = 0.5f*(red[2][0]+red[5][0]);
        float hx = 0.5f*(red[3][0]-red[0][0]);
        float hy = 0.5f*(red[4][0]-red[1][0]);
        float hz = 0.5f*(red[5][0]-red[2][0]);
        float r  = sqrtf(hx*hx + hy*hy + hz*hz);
        bounds[m] = make_float4(cx, cy, cz, r);
    }
}

// ---------------- Pre-pass B: per-(mirror,source) occluder mask (conservative)
__global__ __launch_bounds__(256) void mask_kernel(
    const float* __restrict__ sources,
    const float* __restrict__ cp1g, const float* __restrict__ cp2g,
    const float* __restrict__ crad,
    const float* __restrict__ bp1g, const float* __restrict__ bp2g,
    const float4* __restrict__ bounds, unsigned* __restrict__ masks)
{
    int pair = blockIdx.x * 256 + threadIdx.x;
    if (pair >= NM * NS) return;
    int m = pair / NS;
    int s = pair - m * NS;

    float4 bd = bounds[m];
    float cx = bd.x, cy = bd.y, cz = bd.z;
    float rm = bd.w + PRUNE_MARGIN;
    float sx = sources[s*3+0], sy = sources[s*3+1], sz = sources[s*3+2];

    float d1x = sx - cx, d1y = sy - cy, d1z = sz - cz;
    float a = d1x*d1x + d1y*d1y + d1z*d1z;

    unsigned mask = 0;

    for (int c = 0; c < NCYL; c++) {
        float p2x = cp1g[c*3+0], p2y = cp1g[c*3+1], p2z = cp1g[c*3+2];
        float d2x = cp2g[c*3+0] - p2x, d2y = cp2g[c*3+1] - p2y, d2z = cp2g[c*3+2] - p2z;
        float rx = cx - p2x, ry = cy - p2y, rz = cz - p2z;
        float e = d2x*d2x + d2y*d2y + d2z*d2z;
        float f = d2x*rx + d2y*ry + d2z*rz;
        float cc = d1x*rx + d1y*ry + d1z*rz;
        float b = d1x*d2x + d1y*d2y + d1z*d2z;
        float denom = a*e - b*b;
        float sN = (denom > 1e-6f) ? clamp01((b*f - cc*e) / denom) : 0.0f;
        float tN = (b*sN + f) / e;
        if (tN < 0.0f)      { tN = 0.0f; sN = clamp01(-cc / a); }
        else if (tN > 1.0f) { tN = 1.0f; sN = clamp01((b - cc) / a); }
        float gx = (cx + d1x*sN) - (p2x + d2x*tN);
        float gy = (cy + d1y*sN) - (p2y + d2y*tN);
        float gz = (cz + d1z*sN) - (p2z + d2z*tN);
        float dist2 = gx*gx + gy*gy + gz*gz;
        float thr = crad[c] + rm;
        if (dist2 <= thr*thr) mask |= (1u << c);
    }

    float ivx = 1.0f / ((fabsf(d1x) < FEPS) ? FEPS : d1x);
    float ivy = 1.0f / ((fabsf(d1y) < FEPS) ? FEPS : d1y);
    float ivz = 1.0f / ((fabsf(d1z) < FEPS) ? FEPS : d1z);
    for (int b = 0; b < NBOX; b++) {
        float lx = bp1g[b*3+0] - rm, ly = bp1g[b*3+1] - rm, lz = bp1g[b*3+2] - rm;
        float hx = bp2g[b*3+0] + rm, hy = bp2g[b*3+1] + rm, hz = bp2g[b*3+2] + rm;
        float t0x = (lx - cx) * ivx, t1x = (hx - cx) * ivx;
        float t0y = (ly - cy) * ivy, t1y = (hy - cy) * ivy;
        float t0z = (lz - cz) * ivz, t1z = (hz - cz) * ivz;
        float tmin = fmaxf(fmaxf(fminf(t0x,t1x), fminf(t0y,t1y)), fminf(t0z,t1z));
        float tmax = fminf(fminf(fmaxf(t0x,t1x), fmaxf(t0y,t1y)), fmaxf(t0z,t1z));
        if (fmaxf(tmin, 0.0f) <= fminf(tmax, 1.0f)) mask |= (1u << (16 + b));
    }

    masks[pair] = mask;
}

// ================= Pass 1: rays -> per-tile CONTIGUOUS arena regions
__global__ __launch_bounds__(256) void render_bin_kernel(
    const float* __restrict__ sources, const float* __restrict__ mpts,
    const float* __restrict__ mnrm,    const float* __restrict__ mpos,
    const float* __restrict__ mrot,
    const float* __restrict__ cp1g, const float* __restrict__ cp2g,
    const float* __restrict__ crad, const float* __restrict__ bp1g,
    const float* __restrict__ bp2g, const float* __restrict__ spp,
    const float* __restrict__ spn,  const unsigned* __restrict__ masks,
    unsigned* __restrict__ arena, unsigned* __restrict__ tile_cnt,
    unsigned* __restrict__ valid_end, float* __restrict__ img_direct,
    unsigned tilecap)
{
    __shared__ float4 s_cyl[NCYL][2];
    __shared__ float4 s_box[NBOX][2];
    __shared__ unsigned s_cnt[NTILE];
    __shared__ unsigned s_inc[NTILE];
    __shared__ unsigned s_dst[NTILE];
    __shared__ unsigned s_scratch[256 * SPT];
    __shared__ unsigned short s_tl[256 * SPT];
    __shared__ unsigned s_wsum[4];
    __shared__ unsigned s_of[64][2];
    __shared__ unsigned s_ofn;

    const int t  = threadIdx.x;
    const int n  = blockIdx.x * 256 + t;
    const int s0 = blockIdx.y * SPT;
    const int m  = blockIdx.z;

    const long idx = ((long)m * NP + n) * 3;
    float px = mpts[idx+0], py = mpts[idx+1], pz = mpts[idx+2];
    float nx = mnrm[idx+0], ny = mnrm[idx+1], nz = mnrm[idx+2];

    s_cnt[t] = 0;   // 256 threads == NTILE
    if (t == 0) s_ofn = 0;
    if (t < NCYL) {
        float p1x = cp1g[t*3+0], p1y = cp1g[t*3+1], p1z = cp1g[t*3+2];
        float axx = cp2g[t*3+0] - p1x;
        float axy = cp2g[t*3+1] - p1y;
        float axz = cp2g[t*3+2] - p1z;
        float L   = sqrtf(axx*axx + axy*axy + axz*axz);
        float inv = 1.0f / (L + FEPS);
        float r   = crad[t];
        s_cyl[t][0] = make_float4(p1x, p1y, p1z, L);
        s_cyl[t][1] = make_float4(axx*inv, axy*inv, axz*inv, r*r);
    } else if (t < NCYL + NBOX) {
        int b = t - NCYL;
        s_box[b][0] = make_float4(bp1g[b*3+0], bp1g[b*3+1], bp1g[b*3+2], 0.0f);
        s_box[b][1] = make_float4(bp2g[b*3+0], bp2g[b*3+1], bp2g[b*3+2], 0.0f);
    }
    __syncthreads();

    float R0 = mrot[m*9+0], R1 = mrot[m*9+1], R2 = mrot[m*9+2];
    float R3 = mrot[m*9+3], R4 = mrot[m*9+4], R5 = mrot[m*9+5];
    float R6 = mrot[m*9+6], R7 = mrot[m*9+7], R8 = mrot[m*9+8];
    float posx = mpos[m*3+0], posy = mpos[m*3+1], posz = mpos[m*3+2];
    float sppx = spp[0], sppy = spp[1], sppz = spp[2];
    float spnx = spn[0], spny = spn[1], spnz = spn[2];

    float tpx = R0*px + R1*py + R2*pz + posx;
    float tpy = R3*px + R4*py + R5*pz + posy;
    float tpz = R6*px + R7*py + R8*pz + posz;
    float tnx = R0*nx + R1*ny + R2*nz;
    float tny = R3*nx + R4*ny + R5*nz;
    float tnz = R6*nx + R7*ny + R8*nz;

    float num = (sppx-tpx)*spnx + (sppy-tpy)*spny + (sppz-tpz)*spnz;

    unsigned rec[SPT];
    unsigned rank[SPT];
    int      tileid[SPT];
    unsigned vmask = 0;

    #pragma unroll
    for (int j = 0; j < SPT; j++) {
        const int s = s0 + j;
        float sx = sources[s*3+0], sy = sources[s*3+1], sz = sources[s*3+2];

        float dx = tpx - sx, dy = tpy - sy, dz = tpz - sz;
        float il = frsq(dx*dx + dy*dy + dz*dz);
        dx *= il; dy *= il; dz *= il;
        float ux = -dx, uy = -dy, uz = -dz;

        unsigned pm = masks[(unsigned)m * NS + (unsigned)s];
        pm = __builtin_amdgcn_readfirstlane(pm);
        unsigned cmask = pm & 0xFFFFu;
        unsigned bmask = (pm >> 16) & 0xFFu;

        bool hit = false;

        while (cmask) {
            int c = __builtin_ctz(cmask);
            cmask &= cmask - 1;
            float4 c0 = s_cyl[c][0];
            float4 c1 = s_cyl[c][1];
            float ocx = tpx - c0.x, ocy = tpy - c0.y, ocz = tpz - c0.z;
            float oa  = ocx*c1.x + ocy*c1.y + ocz*c1.z;
            float Cc  = ocx*ocx + ocy*ocy + ocz*ocz - oa*oa - c1.w;
            float ua  = ux*c1.x + uy*c1.y + uz*c1.z;
            float ocu = ux*ocx + uy*ocy + uz*ocz;
            float Bh  = fmaf(-oa, ua, ocu);
            float A   = fmaf(-ua, ua, 1.0f);
            float disc = fmaf(Bh, Bh, -(A*Cc));
            float sq   = fsqrt_(fmaxf(disc, 0.0f));
            float Ah   = A + 0.5f*FEPS;
            float q1   = -Bh - sq;
            float q2   = -Bh + sq;
            float oaA  = oa * Ah;
            float LA   = c0.w * Ah;
            float epsA = FEPS * Ah;
            float ax1A = fmaf(q1, ua, oaA);
            float ax2A = fmaf(q2, ua, oaA);
            bool dpos  = disc > 0.0f;
            hit = hit | (dpos & (q1 > epsA) & (ax1A >= 0.0f) & (ax1A <= LA))
                      | (dpos & (q2 > epsA) & (ax2A >= 0.0f) & (ax2A <= LA));
        }

        if (bmask) {
            float ivx = frcp((fabsf(ux) < FEPS) ? FEPS : ux);
            float ivy = frcp((fabsf(uy) < FEPS) ? FEPS : uy);
            float ivz = frcp((fabsf(uz) < FEPS) ? FEPS : uz);
            while (bmask) {
                int b = __builtin_ctz(bmask);
                bmask &= bmask - 1;
                float4 b1 = s_box[b][0];
                float4 b2 = s_box[b][1];
                float t0x = (b1.x - tpx) * ivx, t1x = (b2.x - tpx) * ivx;
                float t0y = (b1.y - tpy) * ivy, t1y = (b2.y - tpy) * ivy;
                float t0z = (b1.z - tpz) * ivz, t1z = (b2.z - tpz) * ivz;
                float tmin = fmaxf(fmaxf(fminf(t0x,t1x), fminf(t0y,t1y)), fminf(t0z,t1z));
                float tmax = fminf(fminf(fmaxf(t0x,t1x), fmaxf(t0y,t1y)), fmaxf(t0z,t1z));
                hit = hit | (tmax >= fmaxf(tmin, FEPS));
            }
        }

        float dn = dx*tnx + dy*tny + dz*tnz;
        float rx = fmaf(-2.0f*dn, tnx, dx);
        float ry = fmaf(-2.0f*dn, tny, dy);
        float rz = fmaf(-2.0f*dn, tnz, dz);
        float cosv  = fabsf(dn);
        float denom = rx*spnx + ry*spny + rz*spnz;
        float tt = num * frcp(denom + FEPS);
        float qx = fmaf(tt, rx, tpx);
        float qy = fmaf(tt, ry, tpy);
        float fx = (qx + FEXT) * PXSCALE;
        float fy = (qy + FEXT) * PXSCALE;
        float fxf = floorf(fx), fyf = floorf(fy);
        bool inb = (fxf >= 0.0f) & (fxf < (float)IW) & (fyf >= 0.0f) & (fyf < (float)IH)
                   & (!hit);
        if (inb) {
            int ix = (int)fxf, iy = (int)fyf;
            unsigned pix = (unsigned)(iy * IW + ix);
            unsigned q = (unsigned)(cosv * 16383.0f + 0.5f);
            if (q > 16383u) q = 16383u;
            rec[j]    = (pix << 14) | q;
            int tl    = ((iy >> 5) << 4) | (ix >> 5);
            tileid[j] = tl;
            rank[j]   = atomicAdd(&s_cnt[tl], 1u);
            vmask    |= (1u << j);
        }
    }
    __syncthreads();

    // Inclusive scan of s_cnt -> s_inc: shfl wave-scan + 4-entry fixup.
    {
        unsigned v = s_cnt[t];
        const int lane = t & 63;
        #pragma unroll
        for (int off = 1; off < 64; off <<= 1) {
            unsigned x = (unsigned)__shfl_up((int)v, off, 64);
            if (lane >= off) v += x;
        }
        if (lane == 63) s_wsum[t >> 6] = v;
        __syncthreads();
        unsigned w = (unsigned)(t >> 6);
        unsigned basew = 0;
        #pragma unroll
        for (unsigned i = 0; i < 4; i++) if (i < w) basew += s_wsum[i];
        s_inc[t] = v + basew;
        __syncthreads();
    }
    unsigned total = s_wsum[0] + s_wsum[1] + s_wsum[2] + s_wsum[3];

    // Stage records grouped by tile in LDS (with tile tag per slot).
    #pragma unroll
    for (int j = 0; j < SPT; j++) {
        if (vmask & (1u << j)) {
            int tl = tileid[j];
            unsigned off = s_inc[tl] - s_cnt[tl];
            s_scratch[off + rank[j]] = rec[j];
            s_tl[off + rank[j]] = (unsigned short)tl;
        }
    }

    // Per-tile allocation in the contiguous tile arenas (thread t owns tile t).
    unsigned c = s_cnt[t];
    if (c > 0) {
        unsigned off = atomicAdd(&tile_cnt[t], c);
        if (off + c <= tilecap) {
            s_dst[t] = (unsigned)t * tilecap + off;
        } else {
            s_dst[t] = 0xFFFFFFFFu;
            atomicMin(&valid_end[t], off);   // failures form a suffix of allocations
            unsigned k = atomicAdd(&s_ofn, 1u);
            unsigned segoff = s_inc[t] - c;
            if (k < 64u) { s_of[k][0] = segoff; s_of[k][1] = c; }
            else {
                for (unsigned q = 0; q < c; q++) {
                    unsigned r = s_scratch[segoff + q];
                    atomicAdd(&img_direct[r >> 14], (float)(r & 16383u) * (1.0f/16383.0f));
                }
            }
        }
    } else {
        s_dst[t] = 0xFFFFFFFFu;
    }
    __syncthreads();

    // Copy scratch -> per-tile arena regions.
    for (unsigned i = t; i < total; i += 256) {
        unsigned tl = s_tl[i];
        unsigned d  = s_dst[tl];
        if (d != 0xFFFFFFFFu) {
            unsigned segstart = s_inc[tl] - s_cnt[tl];
            arena[(size_t)d + (i - segstart)] = s_scratch[i];
        }
    }

    // Cooperative flush of overflowed segments.
    unsigned nof = s_ofn < 64u ? s_ofn : 64u;
    for (unsigned k = 0; k < nof; k++) {
        unsigned off = s_of[k][0], cc = s_of[k][1];
        for (unsigned i = t; i < cc; i += 256) {
            unsigned r = s_scratch[off + i];
            atomicAdd(&img_direct[r >> 14], (float)(r & 16383u) * (1.0f/16383.0f));
        }
    }
}

// ================= Pass 2: uniform ~TARGET-record blocks.
// Grid = (NTILE, MAXSPLIT); block (t,k) exits (zero-store) if k >= splits_t.
__global__ __launch_bounds__(256) void tile_accum_kernel(
    const uint4* __restrict__ arena4, const unsigned* __restrict__ tile_cnt,
    const unsigned* __restrict__ valid_end, unsigned tilecap,
    float* __restrict__ gimg)
{
    __shared__ float tile[1024];
    const int t   = blockIdx.x;   // tile id
    const int k   = blockIdx.y;   // split index (0..MAXSPLIT-1)
    const int tid = threadIdx.x;

    for (int i = tid; i < 1024; i += 256) tile[i] = 0.0f;

    unsigned cnt = tile_cnt[t];
    unsigned ve  = valid_end[t];
    if (cnt > tilecap) cnt = tilecap;
    if (cnt > ve) cnt = ve;

    unsigned splits = (cnt + TARGET - 1u) / TARGET;
    if (splits < 1u) splits = 1u;
    if (splits > (unsigned)MAXSPLIT) splits = (unsigned)MAXSPLIT;

    const unsigned ty = (unsigned)t >> 4, tx = (unsigned)t & 15;
    float* out = gimg + (size_t)k * NPIX;

    if ((unsigned)k >= splits) {
        // Idle split (rare at TARGET=2048): publish zeros for the reduce.
        __syncthreads();
        for (int i = tid; i < 1024; i += 256) {
            unsigned gy = ty * 32 + (i >> 5);
            unsigned gx = tx * 32 + (i & 31);
            out[gy * IW + gx] = 0.0f;
        }
        return;
    }
    __syncthreads();

    // Slice [lo,hi), lo 4-aligned for uint4 reads.
    unsigned lo = (unsigned)(((unsigned long long)cnt * (unsigned)k) / splits);
    unsigned hi = (unsigned)(((unsigned long long)cnt * (unsigned)(k+1)) / splits);
    lo = (lo + 3u) & ~3u; if (lo > cnt) lo = cnt;
    hi = ((unsigned)k == splits - 1u) ? cnt : ((hi + 3u) & ~3u); if (hi > cnt) hi = cnt;

    const unsigned base4 = (unsigned)t * (tilecap >> 2);

    for (unsigned i0 = lo; i0 < hi; i0 += 2048) {
        uint4 rv[2];
        #pragma unroll
        for (int q = 0; q < 2; q++) {
            unsigned ri = i0 + ((unsigned)tid + (unsigned)(q * 256)) * 4u;
            unsigned v4 = base4 + ((ri < hi ? ri : lo) >> 2);
            rv[q] = arena4[v4];
        }
        #pragma unroll
        for (int q = 0; q < 2; q++) {
            unsigned ri = i0 + ((unsigned)tid + (unsigned)(q * 256)) * 4u;
            unsigned rr[4] = {rv[q].x, rv[q].y, rv[q].z, rv[q].w};
            #pragma unroll
            for (int e = 0; e < 4; e++) {
                unsigned ii = ri + (unsigned)e;
                if (ii < hi) {
                    unsigned pix = rr[e] >> 14;
                    float val = (float)(rr[e] & 16383u) * (1.0f/16383.0f);
                    unsigned ix = pix & 511u, iy = pix >> 9;
                    unsigned lp = ((iy & 31u) << 5) | (ix & 31u);
                    atomicAdd(&tile[lp], val);   // LDS atomic — per-CU
                }
            }
        }
    }
    __syncthreads();

    // (t,k) unique -> plain stores into gimg copy k.
    for (int i = tid; i < 1024; i += 256) {
        unsigned gy = ty * 32 + (i >> 5);
        unsigned gx = tx * 32 + (i & 31);
        out[gy * IW + gx] = tile[i];
    }
}

__global__ __launch_bounds__(256) void reduce_bin_kernel(
    const float4* __restrict__ gimg4, float4* __restrict__ out4)
{
    int i = blockIdx.x * 256 + threadIdx.x;   // over NPIX/4
    float4 v = out4[i];   // direct-flush atomics already landed in out
    #pragma unroll 8
    for (int g = 0; g < MAXSPLIT; g++) {
        float4 a = gimg4[(size_t)g * (NPIX/4) + i];
        v.x += a.x; v.y += a.y; v.z += a.z; v.w += a.w;
    }
    out4[i] = v;
}

// ================= R7 fallback (ws too small): direct-atomic pipeline
__global__ __launch_bounds__(256) void render_kernel(
    const float* __restrict__ sources, const float* __restrict__ mpts,
    const float* __restrict__ mnrm,    const float* __restrict__ mpos,
    const float* __restrict__ mrot,
    const float* __restrict__ cp1g, const float* __restrict__ cp2g,
    const float* __restrict__ crad, const float* __restrict__ bp1g,
    const float* __restrict__ bp2g, const float* __restrict__ spp,
    const float* __restrict__ spn,  const unsigned* __restrict__ masks,
    float* __restrict__ imgs, int K)
{
    __shared__ float4 s_cyl[NCYL][2];
    __shared__ float4 s_box[NBOX][2];

    const int t  = threadIdx.x;
    const int n  = blockIdx.x * 256 + t;
    const int s0 = blockIdx.y * SPT;
    const int m  = blockIdx.z;

    const long idx = ((long)m * NP + n) * 3;
    float px = mpts[idx+0], py = mpts[idx+1], pz = mpts[idx+2];
    float nx = mnrm[idx+0], ny = mnrm[idx+1], nz = mnrm[idx+2];

    if (t < NCYL) {
        float p1x = cp1g[t*3+0], p1y = cp1g[t*3+1], p1z = cp1g[t*3+2];
        float axx = cp2g[t*3+0] - p1x;
        float axy = cp2g[t*3+1] - p1y;
        float axz = cp2g[t*3+2] - p1z;
        float L   = sqrtf(axx*axx + axy*axy + axz*axz);
        float inv = 1.0f / (L + FEPS);
        float r   = crad[t];
        s_cyl[t][0] = make_float4(p1x, p1y, p1z, L);
        s_cyl[t][1] = make_float4(axx*inv, axy*inv, axz*inv, r*r);
    } else if (t < NCYL + NBOX) {
        int b = t - NCYL;
        s_box[b][0] = make_float4(bp1g[b*3+0], bp1g[b*3+1], bp1g[b*3+2], 0.0f);
        s_box[b][1] = make_float4(bp2g[b*3+0], bp2g[b*3+1], bp2g[b*3+2], 0.0f);
    }
    __syncthreads();

    float R0 = mrot[m*9+0], R1 = mrot[m*9+1], R2 = mrot[m*9+2];
    float R3 = mrot[m*9+3], R4 = mrot[m*9+4], R5 = mrot[m*9+5];
    float R6 = mrot[m*9+6], R7 = mrot[m*9+7], R8 = mrot[m*9+8];
    float posx = mpos[m*3+0], posy = mpos[m*3+1], posz = mpos[m*3+2];
    float sppx = spp[0], sppy = spp[1], sppz = spp[2];
    float spnx = spn[0], spny = spn[1], spnz = spn[2];

    float tpx = R0*px + R1*py + R2*pz + posx;
    float tpy = R3*px + R4*py + R5*pz + posy;
    float tpz = R6*px + R7*py + R8*pz + posz;
    float tnx = R0*nx + R1*ny + R2*nz;
    float tny = R3*nx + R4*ny + R5*nz;
    float tnz = R6*nx + R7*ny + R8*nz;

    float num = (sppx-tpx)*spnx + (sppy-tpy)*spny + (sppz-tpz)*spnz;

    int linb = blockIdx.x + (int)gridDim.x * (blockIdx.y + (int)gridDim.y * blockIdx.z);
    float* __restrict__ img = imgs + (size_t)(linb % K) * NPIX;

    for (int j = 0; j < SPT; j++) {
        const int s = s0 + j;
        float sx = sources[s*3+0], sy = sources[s*3+1], sz = sources[s*3+2];

        float dx = tpx - sx, dy = tpy - sy, dz = tpz - sz;
        float il = frsq(dx*dx + dy*dy + dz*dz);
        dx *= il; dy *= il; dz *= il;
        float ux = -dx, uy = -dy, uz = -dz;

        unsigned pm = masks[(unsigned)m * NS + (unsigned)s];
        pm = __builtin_amdgcn_readfirstlane(pm);
        unsigned cmask = pm & 0xFFFFu;
        unsigned bmask = (pm >> 16) & 0xFFu;

        bool hit = false;

        while (cmask) {
            int c = __builtin_ctz(cmask);
            cmask &= cmask - 1;
            float4 c0 = s_cyl[c][0];
            float4 c1 = s_cyl[c][1];
            float ocx = tpx - c0.x, ocy = tpy - c0.y, ocz = tpz - c0.z;
            float oa  = ocx*c1.x + ocy*c1.y + ocz*c1.z;
            float Cc  = ocx*ocx + ocy*ocy + ocz*ocz - oa*oa - c1.w;
            float ua  = ux*c1.x + uy*c1.y + uz*c1.z;
            float ocu = ux*ocx + uy*ocy + uz*ocz;
            float Bh  = fmaf(-oa, ua, ocu);
            float A   = fmaf(-ua, ua, 1.0f);
            float disc = fmaf(Bh, Bh, -(A*Cc));
            float sq   = fsqrt_(fmaxf(disc, 0.0f));
            float Ah   = A + 0.5f*FEPS;
            float q1   = -Bh - sq;
            float q2   = -Bh + sq;
            float oaA  = oa * Ah;
            float LA   = c0.w * Ah;
            float epsA = FEPS * Ah;
            float ax1A = fmaf(q1, ua, oaA);
            float ax2A = fmaf(q2, ua, oaA);
            bool dpos  = disc > 0.0f;
            hit = hit | (dpos & (q1 > epsA) & (ax1A >= 0.0f) & (ax1A <= LA))
                      | (dpos & (q2 > epsA) & (ax2A >= 0.0f) & (ax2A <= LA));
        }

        if (bmask) {
            float ivx = frcp((fabsf(ux) < FEPS) ? FEPS : ux);
            float ivy = frcp((fabsf(uy) < FEPS) ? FEPS : uy);
            float ivz = frcp((fabsf(uz) < FEPS) ? FEPS : uz);
            while (bmask) {
                int b = __builtin_ctz(bmask);
                bmask &= bmask - 1;
                float4 b1 = s_box[b][0];
                float4 b2 = s_box[b][1];
                float t0x = (b1.x - tpx) * ivx, t1x = (b2.x - tpx) * ivx;
                float t0y = (b1.y - tpy) * ivy, t1y = (b2.y - tpy) * ivy;
                float t0z = (b1.z - tpz) * ivz, t1z = (b2.z - tpz) * ivz;
                float tmin = fmaxf(fmaxf(fminf(t0x,t1x), fminf(t0y,t1y)), fminf(t0z,t1z));
                float tmax = fminf(fminf(fmaxf(t0x,t1x), fmaxf(t0y,t1y)), fmaxf(t0z,t1z));
                hit = hit | (tmax >= fmaxf(tmin, FEPS));
            }
        }

        {
            float dn = dx*tnx + dy*tny + dz*tnz;
            float rx = fmaf(-2.0f*dn, tnx, dx);
            float ry = fmaf(-2.0f*dn, tny, dy);
            float rz = fmaf(-2.0f*dn, tnz, dz);
            float cosv  = fabsf(dn);
            float denom = rx*spnx + ry*spny + rz*spnz;
            float tt = num * frcp(denom + FEPS);
            float qx = fmaf(tt, rx, tpx);
            float qy = fmaf(tt, ry, tpy);
            float fx = (qx + FEXT) * PXSCALE;
            float fy = (qy + FEXT) * PXSCALE;
            float fxf = floorf(fx), fyf = floorf(fy);
            bool inb = (fxf >= 0.0f) & (fxf < (float)IW) & (fyf >= 0.0f) & (fyf < (float)IH)
                       & (!hit);
            if (inb) atomicAdd(&img[(int)fyf * IW + (int)fxf], cosv);
        }
    }
}

__global__ __launch_bounds__(256) void reduce_kernel(
    const float* __restrict__ imgs, int K, float* __restrict__ out)
{
    int i = blockIdx.x * 256 + threadIdx.x;
    float v = 0.0f;
    for (int k = 0; k < K; k++) v += imgs[(size_t)k * NPIX + i];
    out[i] = v;
}

extern "C" void kernel_launch(void* const* d_in, const int* in_sizes, int n_in,
                              void* d_out, int out_size, void* d_ws, size_t ws_size,
                              hipStream_t stream) {
    const float* sources = (const float*)d_in[0];
    const float* mpts    = (const float*)d_in[1];
    const float* mnrm    = (const float*)d_in[2];
    const float* mpos    = (const float*)d_in[3];
    const float* mrot    = (const float*)d_in[4];
    const float* cp1     = (const float*)d_in[5];
    const float* cp2     = (const float*)d_in[6];
    const float* crad    = (const float*)d_in[7];
    const float* bp1     = (const float*)d_in[8];
    const float* bp2     = (const float*)d_in[9];
    const float* spp     = (const float*)d_in[10];
    const float* spn     = (const float*)d_in[11];

    const size_t CNT_BYTES = 4096;
    const size_t BND_BYTES = 1024;
    const size_t MSK_BYTES = (size_t)NM * NS * 4u;   // 32 KiB
    const size_t GIMG_BYTES = (size_t)MAXSPLIT * NPIX * 4u;   // 32 MiB

    // Adaptive tilecap (multiple of 4): prefer capacity.
    unsigned tilecap = 0;
    {
        const unsigned cap_opts[4] = {262144u, 196608u, 131072u, 65536u};
        for (int ci = 0; ci < 4; ci++) {
            size_t need = (size_t)NTILE * cap_opts[ci] * 4u + GIMG_BYTES
                        + CNT_BYTES + BND_BYTES + MSK_BYTES;
            if (need <= ws_size) { tilecap = cap_opts[ci]; break; }
        }
    }

    if (tilecap > 0) {
        // ---------- descriptor-free binning pipeline ----------
        char* p = (char*)d_ws;
        unsigned* arena     = (unsigned*)p;               p += (size_t)NTILE * tilecap * 4u;
        float*    gimg      = (float*)p;                  p += GIMG_BYTES;
        unsigned* tile_cnt  = (unsigned*)p;               // [0..255]
        unsigned* valid_end = tile_cnt + 256;             // [256..511]
        p += CNT_BYTES;
        float4*   bounds    = (float4*)p;                 p += BND_BYTES;
        unsigned* masks     = (unsigned*)p;

        hipMemsetAsync(tile_cnt, 0, 1024, stream);
        hipMemsetAsync(valid_end, 0xFF, 1024, stream);    // ~0u = no overflow
        hipMemsetAsync(d_out, 0, (size_t)NPIX * sizeof(float), stream);

        mirror_bounds_kernel<<<NM, 256, 0, stream>>>(mpts, mpos, mrot, bounds);
        mask_kernel<<<(NM * NS + 255) / 256, 256, 0, stream>>>(
            sources, cp1, cp2, crad, bp1, bp2, bounds, masks);

        dim3 grid(NP / 256, NS / SPT, NM);   // (8,16,64) = 8192 blocks
        render_bin_kernel<<<grid, 256, 0, stream>>>(
            sources, mpts, mnrm, mpos, mrot, cp1, cp2, crad, bp1, bp2, spp, spn,
            masks, arena, tile_cnt, valid_end, (float*)d_out, tilecap);

        dim3 grid2(NTILE, MAXSPLIT);         // 256 x 32; nearly all blocks active
        tile_accum_kernel<<<grid2, 256, 0, stream>>>((const uint4*)arena, tile_cnt,
                                                     valid_end, tilecap, gimg);

        reduce_bin_kernel<<<(NPIX/4) / 256, 256, 0, stream>>>(
            (const float4*)gimg, (float4*)d_out);
    } else {
        // ---------- R7 fallback: direct atomics with K privatized images ----------
        const size_t IMG_BYTES = (size_t)NPIX * sizeof(float);
        const size_t AUX_BYTES = 1024 + (size_t)NM * NS * sizeof(unsigned);
        int K = 0;
        for (int k = 8; k >= 1; k >>= 1) {
            if ((size_t)k * IMG_BYTES + AUX_BYTES <= ws_size) { K = k; break; }
        }
        float* imgs;
        char*  aux;
        if (K >= 1) {
            imgs = (float*)d_ws;
            aux  = (char*)d_ws + (size_t)K * IMG_BYTES;
            hipMemsetAsync(imgs, 0, (size_t)K * IMG_BYTES, stream);
        } else {
            K    = 1;
            imgs = (float*)d_out;
            aux  = (char*)d_ws;
            hipMemsetAsync(imgs, 0, IMG_BYTES, stream);
        }
        float4*   bounds = (float4*)aux;
        unsigned* masks  = (unsigned*)(aux + 1024);

        mirror_bounds_kernel<<<NM, 256, 0, stream>>>(mpts, mpos, mrot, bounds);
        mask_kernel<<<(NM * NS + 255) / 256, 256, 0, stream>>>(
            sources, cp1, cp2, crad, bp1, bp2, bounds, masks);

        dim3 grid(NP / 256, NS / SPT, NM);
        render_kernel<<<grid, 256, 0, stream>>>(sources, mpts, mnrm, mpos, mrot,
                                                cp1, cp2, crad, bp1, bp2, spp, spn,
                                                masks, imgs, K);
        if (imgs != (float*)d_out) {
            reduce_kernel<<<NPIX / 256, 256, 0, stream>>>(imgs, K, (float*)d_out);
        }
    }
}

// Round 18
// 327.540 us; speedup vs baseline: 1.0561x; 1.0561x over previous
//
#include <hip/hip_runtime.h>

// S,P,M=(128,2048,64), NC,NB=(16,8), H,W=512, EXTENT=12, EPS=1e-9
#define NS   128
#define NP   2048
#define NM   64
#define NCYL 16
#define NBOX 8
#define IH   512
#define IW   512
#define NPIX (IH*IW)
#define FEXT 12.0f
#define FEPS 1e-9f
#define PXSCALE ((float)IW / (2.0f * FEXT))
#define PRUNE_MARGIN 0.05f
#define SPT  8       // sources per thread
#define NTILE 256    // 16x16 grid of 32x32-pixel tiles
#define MAXSPLIT 64  // max pass-2 blocks per tile (gimg copies)
#define TARGET 4096u // records per pass-2 block (R16 empirical optimum)

__device__ __forceinline__ float frcp(float x)   { return __builtin_amdgcn_rcpf(x); }
__device__ __forceinline__ float frsq(float x)   { return __builtin_amdgcn_rsqf(x); }
__device__ __forceinline__ float fsqrt_(float x) { return __builtin_amdgcn_sqrtf(x); }
__device__ __forceinline__ float clamp01(float x){ return fminf(fmaxf(x, 0.0f), 1.0f); }

__device__ __forceinline__ unsigned eff_cnt(const unsigned* tile_cnt,
                                            const unsigned* valid_end,
                                            int t, unsigned tilecap)
{
    unsigned cnt = tile_cnt[t];
    unsigned ve  = valid_end[t];
    if (cnt > tilecap) cnt = tilecap;
    if (cnt > ve) cnt = ve;
    return cnt;
}

__device__ __forceinline__ unsigned n_splits(unsigned cnt)
{
    unsigned s = (cnt + TARGET - 1u) / TARGET;
    if (s < 1u) s = 1u;
    if (s > (unsigned)MAXSPLIT) s = (unsigned)MAXSPLIT;
    return s;
}

// ---------------- Pre-pass A: per-mirror bounding sphere of transformed points
__global__ __launch_bounds__(256) void mirror_bounds_kernel(
    const float* __restrict__ mpts, const float* __restrict__ mpos,
    const float* __restrict__ mrot, float4* __restrict__ bounds)
{
    const int m = blockIdx.x;
    const int t = threadIdx.x;
    float R0 = mrot[m*9+0], R1 = mrot[m*9+1], R2 = mrot[m*9+2];
    float R3 = mrot[m*9+3], R4 = mrot[m*9+4], R5 = mrot[m*9+5];
    float R6 = mrot[m*9+6], R7 = mrot[m*9+7], R8 = mrot[m*9+8];
    float posx = mpos[m*3+0], posy = mpos[m*3+1], posz = mpos[m*3+2];

    float mnx = 1e30f, mny = 1e30f, mnz = 1e30f;
    float mxx = -1e30f, mxy = -1e30f, mxz = -1e30f;
    for (int i = t; i < NP; i += 256) {
        long id = ((long)m * NP + i) * 3;
        float px = mpts[id+0], py = mpts[id+1], pz = mpts[id+2];
        float tx = R0*px + R1*py + R2*pz + posx;
        float ty = R3*px + R4*py + R5*pz + posy;
        float tz = R6*px + R7*py + R8*pz + posz;
        mnx = fminf(mnx, tx); mny = fminf(mny, ty); mnz = fminf(mnz, tz);
        mxx = fmaxf(mxx, tx); mxy = fmaxf(mxy, ty); mxz = fmaxf(mxz, tz);
    }
    __shared__ float red[6][256];
    red[0][t] = mnx; red[1][t] = mny; red[2][t] = mnz;
    red[3][t] = mxx; red[4][t] = mxy; red[5][t] = mxz;
    __syncthreads();
    for (int off = 128; off > 0; off >>= 1) {
        if (t < off) {
            red[0][t] = fminf(red[0][t], red[0][t+off]);
            red[1][t] = fminf(red[1][t], red[1][t+off]);
            red[2][t] = fminf(red[2][t], red[2][t+off]);
            red[3][t] = fmaxf(red[3][t], red[3][t+off]);
            red[4][t] = fmaxf(red[4][t], red[4][t+off]);
            red[5][t] = fmaxf(red[5][t], red[5][t+off]);
        }
        __syncthreads();
    }
    if (t == 0) {
        float cx = 0.5f*(red[0][0]+red[3][0]);
        float cy = 0.5f*(red[1][0]+red[4][0]);
        float cz = 0.5f*(red[2][0]+red[5][0]);
        float hx = 0.5f*(red[3][0]-red[0][0]);
        float hy = 0.5f*(red[4][0]-red[1][0]);
        float hz = 0.5f*(red[5][0]-red[2][0]);
        float r  = sqrtf(hx*hx + hy*hy + hz*hz);
        bounds[m] = make_float4(cx, cy, cz, r);
    }
}

// ---------------- Pre-pass B: per-(mirror,source) occluder mask (conservative)
__global__ __launch_bounds__(256) void mask_kernel(
    const float* __restrict__ sources,
    const float* __restrict__ cp1g, const float* __restrict__ cp2g,
    const float* __restrict__ crad,
    const float* __restrict__ bp1g, const float* __restrict__ bp2g,
    const float4* __restrict__ bounds, unsigned* __restrict__ masks)
{
    int pair = blockIdx.x * 256 + threadIdx.x;
    if (pair >= NM * NS) return;
    int m = pair / NS;
    int s = pair - m * NS;

    float4 bd = bounds[m];
    float cx = bd.x, cy = bd.y, cz = bd.z;
    float rm = bd.w + PRUNE_MARGIN;
    float sx = sources[s*3+0], sy = sources[s*3+1], sz = sources[s*3+2];

    float d1x = sx - cx, d1y = sy - cy, d1z = sz - cz;
    float a = d1x*d1x + d1y*d1y + d1z*d1z;

    unsigned mask = 0;

    for (int c = 0; c < NCYL; c++) {
        float p2x = cp1g[c*3+0], p2y = cp1g[c*3+1], p2z = cp1g[c*3+2];
        float d2x = cp2g[c*3+0] - p2x, d2y = cp2g[c*3+1] - p2y, d2z = cp2g[c*3+2] - p2z;
        float rx = cx - p2x, ry = cy - p2y, rz = cz - p2z;
        float e = d2x*d2x + d2y*d2y + d2z*d2z;
        float f = d2x*rx + d2y*ry + d2z*rz;
        float cc = d1x*rx + d1y*ry + d1z*rz;
        float b = d1x*d2x + d1y*d2y + d1z*d2z;
        float denom = a*e - b*b;
        float sN = (denom > 1e-6f) ? clamp01((b*f - cc*e) / denom) : 0.0f;
        float tN = (b*sN + f) / e;
        if (tN < 0.0f)      { tN = 0.0f; sN = clamp01(-cc / a); }
        else if (tN > 1.0f) { tN = 1.0f; sN = clamp01((b - cc) / a); }
        float gx = (cx + d1x*sN) - (p2x + d2x*tN);
        float gy = (cy + d1y*sN) - (p2y + d2y*tN);
        float gz = (cz + d1z*sN) - (p2z + d2z*tN);
        float dist2 = gx*gx + gy*gy + gz*gz;
        float thr = crad[c] + rm;
        if (dist2 <= thr*thr) mask |= (1u << c);
    }

    float ivx = 1.0f / ((fabsf(d1x) < FEPS) ? FEPS : d1x);
    float ivy = 1.0f / ((fabsf(d1y) < FEPS) ? FEPS : d1y);
    float ivz = 1.0f / ((fabsf(d1z) < FEPS) ? FEPS : d1z);
    for (int b = 0; b < NBOX; b++) {
        float lx = bp1g[b*3+0] - rm, ly = bp1g[b*3+1] - rm, lz = bp1g[b*3+2] - rm;
        float hx = bp2g[b*3+0] + rm, hy = bp2g[b*3+1] + rm, hz = bp2g[b*3+2] + rm;
        float t0x = (lx - cx) * ivx, t1x = (hx - cx) * ivx;
        float t0y = (ly - cy) * ivy, t1y = (hy - cy) * ivy;
        float t0z = (lz - cz) * ivz, t1z = (hz - cz) * ivz;
        float tmin = fmaxf(fmaxf(fminf(t0x,t1x), fminf(t0y,t1y)), fminf(t0z,t1z));
        float tmax = fminf(fminf(fmaxf(t0x,t1x), fmaxf(t0y,t1y)), fmaxf(t0z,t1z));
        if (fmaxf(tmin, 0.0f) <= fminf(tmax, 1.0f)) mask |= (1u << (16 + b));
    }

    masks[pair] = mask;
}

// ================= Pass 1: rays -> per-tile CONTIGUOUS arena regions
__global__ __launch_bounds__(256) void render_bin_kernel(
    const float* __restrict__ sources, const float* __restrict__ mpts,
    const float* __restrict__ mnrm,    const float* __restrict__ mpos,
    const float* __restrict__ mrot,
    const float* __restrict__ cp1g, const float* __restrict__ cp2g,
    const float* __restrict__ crad, const float* __restrict__ bp1g,
    const float* __restrict__ bp2g, const float* __restrict__ spp,
    const float* __restrict__ spn,  const unsigned* __restrict__ masks,
    unsigned* __restrict__ arena, unsigned* __restrict__ tile_cnt,
    unsigned* __restrict__ valid_end, float* __restrict__ img_direct,
    unsigned tilecap)
{
    __shared__ float4 s_cyl[NCYL][2];
    __shared__ float4 s_box[NBOX][2];
    __shared__ unsigned s_cnt[NTILE];
    __shared__ unsigned s_inc[NTILE];
    __shared__ unsigned s_dst[NTILE];
    __shared__ unsigned s_scratch[256 * SPT];
    __shared__ unsigned short s_tl[256 * SPT];
    __shared__ unsigned s_wsum[4];
    __shared__ unsigned s_of[64][2];
    __shared__ unsigned s_ofn;

    const int t  = threadIdx.x;
    const int n  = blockIdx.x * 256 + t;
    const int s0 = blockIdx.y * SPT;
    const int m  = blockIdx.z;

    const long idx = ((long)m * NP + n) * 3;
    float px = mpts[idx+0], py = mpts[idx+1], pz = mpts[idx+2];
    float nx = mnrm[idx+0], ny = mnrm[idx+1], nz = mnrm[idx+2];

    s_cnt[t] = 0;   // 256 threads == NTILE
    if (t == 0) s_ofn = 0;
    if (t < NCYL) {
        float p1x = cp1g[t*3+0], p1y = cp1g[t*3+1], p1z = cp1g[t*3+2];
        float axx = cp2g[t*3+0] - p1x;
        float axy = cp2g[t*3+1] - p1y;
        float axz = cp2g[t*3+2] - p1z;
        float L   = sqrtf(axx*axx + axy*axy + axz*axz);
        float inv = 1.0f / (L + FEPS);
        float r   = crad[t];
        s_cyl[t][0] = make_float4(p1x, p1y, p1z, L);
        s_cyl[t][1] = make_float4(axx*inv, axy*inv, axz*inv, r*r);
    } else if (t < NCYL + NBOX) {
        int b = t - NCYL;
        s_box[b][0] = make_float4(bp1g[b*3+0], bp1g[b*3+1], bp1g[b*3+2], 0.0f);
        s_box[b][1] = make_float4(bp2g[b*3+0], bp2g[b*3+1], bp2g[b*3+2], 0.0f);
    }
    __syncthreads();

    float R0 = mrot[m*9+0], R1 = mrot[m*9+1], R2 = mrot[m*9+2];
    float R3 = mrot[m*9+3], R4 = mrot[m*9+4], R5 = mrot[m*9+5];
    float R6 = mrot[m*9+6], R7 = mrot[m*9+7], R8 = mrot[m*9+8];
    float posx = mpos[m*3+0], posy = mpos[m*3+1], posz = mpos[m*3+2];
    float sppx = spp[0], sppy = spp[1], sppz = spp[2];
    float spnx = spn[0], spny = spn[1], spnz = spn[2];

    float tpx = R0*px + R1*py + R2*pz + posx;
    float tpy = R3*px + R4*py + R5*pz + posy;
    float tpz = R6*px + R7*py + R8*pz + posz;
    float tnx = R0*nx + R1*ny + R2*nz;
    float tny = R3*nx + R4*ny + R5*nz;
    float tnz = R6*nx + R7*ny + R8*nz;

    float num = (sppx-tpx)*spnx + (sppy-tpy)*spny + (sppz-tpz)*spnz;

    unsigned rec[SPT];
    unsigned rank[SPT];
    int      tileid[SPT];
    unsigned vmask = 0;

    #pragma unroll
    for (int j = 0; j < SPT; j++) {
        const int s = s0 + j;
        float sx = sources[s*3+0], sy = sources[s*3+1], sz = sources[s*3+2];

        float dx = tpx - sx, dy = tpy - sy, dz = tpz - sz;
        float il = frsq(dx*dx + dy*dy + dz*dz);
        dx *= il; dy *= il; dz *= il;
        float ux = -dx, uy = -dy, uz = -dz;

        unsigned pm = masks[(unsigned)m * NS + (unsigned)s];
        pm = __builtin_amdgcn_readfirstlane(pm);
        unsigned cmask = pm & 0xFFFFu;
        unsigned bmask = (pm >> 16) & 0xFFu;

        bool hit = false;

        while (cmask) {
            int c = __builtin_ctz(cmask);
            cmask &= cmask - 1;
            float4 c0 = s_cyl[c][0];
            float4 c1 = s_cyl[c][1];
            float ocx = tpx - c0.x, ocy = tpy - c0.y, ocz = tpz - c0.z;
            float oa  = ocx*c1.x + ocy*c1.y + ocz*c1.z;
            float Cc  = ocx*ocx + ocy*ocy + ocz*ocz - oa*oa - c1.w;
            float ua  = ux*c1.x + uy*c1.y + uz*c1.z;
            float ocu = ux*ocx + uy*ocy + uz*ocz;
            float Bh  = fmaf(-oa, ua, ocu);
            float A   = fmaf(-ua, ua, 1.0f);
            float disc = fmaf(Bh, Bh, -(A*Cc));
            float sq   = fsqrt_(fmaxf(disc, 0.0f));
            float Ah   = A + 0.5f*FEPS;
            float q1   = -Bh - sq;
            float q2   = -Bh + sq;
            float oaA  = oa * Ah;
            float LA   = c0.w * Ah;
            float epsA = FEPS * Ah;
            float ax1A = fmaf(q1, ua, oaA);
            float ax2A = fmaf(q2, ua, oaA);
            bool dpos  = disc > 0.0f;
            hit = hit | (dpos & (q1 > epsA) & (ax1A >= 0.0f) & (ax1A <= LA))
                      | (dpos & (q2 > epsA) & (ax2A >= 0.0f) & (ax2A <= LA));
        }

        if (bmask) {
            float ivx = frcp((fabsf(ux) < FEPS) ? FEPS : ux);
            float ivy = frcp((fabsf(uy) < FEPS) ? FEPS : uy);
            float ivz = frcp((fabsf(uz) < FEPS) ? FEPS : uz);
            while (bmask) {
                int b = __builtin_ctz(bmask);
                bmask &= bmask - 1;
                float4 b1 = s_box[b][0];
                float4 b2 = s_box[b][1];
                float t0x = (b1.x - tpx) * ivx, t1x = (b2.x - tpx) * ivx;
                float t0y = (b1.y - tpy) * ivy, t1y = (b2.y - tpy) * ivy;
                float t0z = (b1.z - tpz) * ivz, t1z = (b2.z - tpz) * ivz;
                float tmin = fmaxf(fmaxf(fminf(t0x,t1x), fminf(t0y,t1y)), fminf(t0z,t1z));
                float tmax = fminf(fminf(fmaxf(t0x,t1x), fmaxf(t0y,t1y)), fmaxf(t0z,t1z));
                hit = hit | (tmax >= fmaxf(tmin, FEPS));
            }
        }

        float dn = dx*tnx + dy*tny + dz*tnz;
        float rx = fmaf(-2.0f*dn, tnx, dx);
        float ry = fmaf(-2.0f*dn, tny, dy);
        float rz = fmaf(-2.0f*dn, tnz, dz);
        float cosv  = fabsf(dn);
        float denom = rx*spnx + ry*spny + rz*spnz;
        float tt = num * frcp(denom + FEPS);
        float qx = fmaf(tt, rx, tpx);
        float qy = fmaf(tt, ry, tpy);
        float fx = (qx + FEXT) * PXSCALE;
        float fy = (qy + FEXT) * PXSCALE;
        float fxf = floorf(fx), fyf = floorf(fy);
        bool inb = (fxf >= 0.0f) & (fxf < (float)IW) & (fyf >= 0.0f) & (fyf < (float)IH)
                   & (!hit);
        if (inb) {
            int ix = (int)fxf, iy = (int)fyf;
            unsigned pix = (unsigned)(iy * IW + ix);
            unsigned q = (unsigned)(cosv * 16383.0f + 0.5f);
            if (q > 16383u) q = 16383u;
            rec[j]    = (pix << 14) | q;
            int tl    = ((iy >> 5) << 4) | (ix >> 5);
            tileid[j] = tl;
            rank[j]   = atomicAdd(&s_cnt[tl], 1u);
            vmask    |= (1u << j);
        }
    }
    __syncthreads();

    // Inclusive scan of s_cnt -> s_inc: shfl wave-scan + 4-entry fixup.
    {
        unsigned v = s_cnt[t];
        const int lane = t & 63;
        #pragma unroll
        for (int off = 1; off < 64; off <<= 1) {
            unsigned x = (unsigned)__shfl_up((int)v, off, 64);
            if (lane >= off) v += x;
        }
        if (lane == 63) s_wsum[t >> 6] = v;
        __syncthreads();
        unsigned w = (unsigned)(t >> 6);
        unsigned basew = 0;
        #pragma unroll
        for (unsigned i = 0; i < 4; i++) if (i < w) basew += s_wsum[i];
        s_inc[t] = v + basew;
        __syncthreads();
    }
    unsigned total = s_wsum[0] + s_wsum[1] + s_wsum[2] + s_wsum[3];

    // Stage records grouped by tile in LDS (with tile tag per slot).
    #pragma unroll
    for (int j = 0; j < SPT; j++) {
        if (vmask & (1u << j)) {
            int tl = tileid[j];
            unsigned off = s_inc[tl] - s_cnt[tl];
            s_scratch[off + rank[j]] = rec[j];
            s_tl[off + rank[j]] = (unsigned short)tl;
        }
    }

    // Per-tile allocation in the contiguous tile arenas (thread t owns tile t).
    unsigned c = s_cnt[t];
    if (c > 0) {
        unsigned off = atomicAdd(&tile_cnt[t], c);
        if (off + c <= tilecap) {
            s_dst[t] = (unsigned)t * tilecap + off;
        } else {
            s_dst[t] = 0xFFFFFFFFu;
            atomicMin(&valid_end[t], off);   // failures form a suffix of allocations
            unsigned k = atomicAdd(&s_ofn, 1u);
            unsigned segoff = s_inc[t] - c;
            if (k < 64u) { s_of[k][0] = segoff; s_of[k][1] = c; }
            else {
                for (unsigned q = 0; q < c; q++) {
                    unsigned r = s_scratch[segoff + q];
                    atomicAdd(&img_direct[r >> 14], (float)(r & 16383u) * (1.0f/16383.0f));
                }
            }
        }
    } else {
        s_dst[t] = 0xFFFFFFFFu;
    }
    __syncthreads();

    // Copy scratch -> per-tile arena regions.
    for (unsigned i = t; i < total; i += 256) {
        unsigned tl = s_tl[i];
        unsigned d  = s_dst[tl];
        if (d != 0xFFFFFFFFu) {
            unsigned segstart = s_inc[tl] - s_cnt[tl];
            arena[(size_t)d + (i - segstart)] = s_scratch[i];
        }
    }

    // Cooperative flush of overflowed segments.
    unsigned nof = s_ofn < 64u ? s_ofn : 64u;
    for (unsigned k = 0; k < nof; k++) {
        unsigned off = s_of[k][0], cc = s_of[k][1];
        for (unsigned i = t; i < cc; i += 256) {
            unsigned r = s_scratch[off + i];
            atomicAdd(&img_direct[r >> 14], (float)(r & 16383u) * (1.0f/16383.0f));
        }
    }
}

// ================= Pass 2 (R16 optimum): 4-deep uint4, idle splits exit
// immediately with NO stores — reduce knows splits_t and skips dead slots.
__global__ __launch_bounds__(256) void tile_accum_kernel(
    const uint4* __restrict__ arena4, const unsigned* __restrict__ tile_cnt,
    const unsigned* __restrict__ valid_end, unsigned tilecap,
    float* __restrict__ gimg)
{
    __shared__ float tile[1024];
    const int t   = blockIdx.x;   // tile id
    const int k   = blockIdx.y;   // split index (0..MAXSPLIT-1)
    const int tid = threadIdx.x;

    unsigned cnt = eff_cnt(tile_cnt, valid_end, t, tilecap);
    unsigned splits = n_splits(cnt);
    if ((unsigned)k >= splits) return;   // idle: no stores, no barrier needed yet

    for (int i = tid; i < 1024; i += 256) tile[i] = 0.0f;
    __syncthreads();

    // Slice [lo,hi), lo 4-aligned for uint4 reads.
    unsigned lo = (unsigned)(((unsigned long long)cnt * (unsigned)k) / splits);
    unsigned hi = (unsigned)(((unsigned long long)cnt * (unsigned)(k+1)) / splits);
    lo = (lo + 3u) & ~3u; if (lo > cnt) lo = cnt;
    hi = ((unsigned)k == splits - 1u) ? cnt : ((hi + 3u) & ~3u); if (hi > cnt) hi = cnt;

    const unsigned base4 = (unsigned)t * (tilecap >> 2);

    for (unsigned i0 = lo; i0 < hi; i0 += 4096) {
        uint4 rv[4];
        #pragma unroll
        for (int q = 0; q < 4; q++) {
            unsigned ri = i0 + ((unsigned)tid + (unsigned)(q * 256)) * 4u;
            unsigned v4 = base4 + ((ri < hi ? ri : lo) >> 2);
            rv[q] = arena4[v4];
        }
        #pragma unroll
        for (int q = 0; q < 4; q++) {
            unsigned ri = i0 + ((unsigned)tid + (unsigned)(q * 256)) * 4u;
            unsigned rr[4] = {rv[q].x, rv[q].y, rv[q].z, rv[q].w};
            #pragma unroll
            for (int e = 0; e < 4; e++) {
                unsigned ii = ri + (unsigned)e;
                if (ii < hi) {
                    unsigned pix = rr[e] >> 14;
                    float val = (float)(rr[e] & 16383u) * (1.0f/16383.0f);
                    unsigned ix = pix & 511u, iy = pix >> 9;
                    unsigned lp = ((iy & 31u) << 5) | (ix & 31u);
                    atomicAdd(&tile[lp], val);   // LDS atomic — per-CU
                }
            }
        }
    }
    __syncthreads();

    const unsigned ty = (unsigned)t >> 4, tx = (unsigned)t & 15;
    float* out = gimg + (size_t)k * NPIX;
    for (int i = tid; i < 1024; i += 256) {
        unsigned gy = ty * 32 + (i >> 5);
        unsigned gx = tx * 32 + (i & 31);
        out[gy * IW + gx] = tile[i];
    }
}

// Splits-aware reduce: each 4-aligned float4 lies in one tile; only the
// active gimg slots for that tile are read (dead slots hold poison).
__global__ __launch_bounds__(256) void reduce_bin_kernel(
    const float4* __restrict__ gimg4, const unsigned* __restrict__ tile_cnt,
    const unsigned* __restrict__ valid_end, unsigned tilecap,
    float4* __restrict__ out4)
{
    int i = blockIdx.x * 256 + threadIdx.x;   // over NPIX/4
    unsigned pix0 = (unsigned)i * 4u;
    unsigned ix = pix0 & 511u, iy = pix0 >> 9;
    int t = (int)(((iy >> 5) << 4) | (ix >> 5));

    unsigned cnt = eff_cnt(tile_cnt, valid_end, t, tilecap);
    unsigned splits = n_splits(cnt);

    float4 v = out4[i];   // direct-flush atomics already landed in out
    for (unsigned g = 0; g < splits; g++) {
        float4 a = gimg4[(size_t)g * (NPIX/4) + i];
        v.x += a.x; v.y += a.y; v.z += a.z; v.w += a.w;
    }
    out4[i] = v;
}

// ================= R7 fallback (ws too small): direct-atomic pipeline
__global__ __launch_bounds__(256) void render_kernel(
    const float* __restrict__ sources, const float* __restrict__ mpts,
    const float* __restrict__ mnrm,    const float* __restrict__ mpos,
    const float* __restrict__ mrot,
    const float* __restrict__ cp1g, const float* __restrict__ cp2g,
    const float* __restrict__ crad, const float* __restrict__ bp1g,
    const float* __restrict__ bp2g, const float* __restrict__ spp,
    const float* __restrict__ spn,  const unsigned* __restrict__ masks,
    float* __restrict__ imgs, int K)
{
    __shared__ float4 s_cyl[NCYL][2];
    __shared__ float4 s_box[NBOX][2];

    const int t  = threadIdx.x;
    const int n  = blockIdx.x * 256 + t;
    const int s0 = blockIdx.y * SPT;
    const int m  = blockIdx.z;

    const long idx = ((long)m * NP + n) * 3;
    float px = mpts[idx+0], py = mpts[idx+1], pz = mpts[idx+2];
    float nx = mnrm[idx+0], ny = mnrm[idx+1], nz = mnrm[idx+2];

    if (t < NCYL) {
        float p1x = cp1g[t*3+0], p1y = cp1g[t*3+1], p1z = cp1g[t*3+2];
        float axx = cp2g[t*3+0] - p1x;
        float axy = cp2g[t*3+1] - p1y;
        float axz = cp2g[t*3+2] - p1z;
        float L   = sqrtf(axx*axx + axy*axy + axz*axz);
        float inv = 1.0f / (L + FEPS);
        float r   = crad[t];
        s_cyl[t][0] = make_float4(p1x, p1y, p1z, L);
        s_cyl[t][1] = make_float4(axx*inv, axy*inv, axz*inv, r*r);
    } else if (t < NCYL + NBOX) {
        int b = t - NCYL;
        s_box[b][0] = make_float4(bp1g[b*3+0], bp1g[b*3+1], bp1g[b*3+2], 0.0f);
        s_box[b][1] = make_float4(bp2g[b*3+0], bp2g[b*3+1], bp2g[b*3+2], 0.0f);
    }
    __syncthreads();

    float R0 = mrot[m*9+0], R1 = mrot[m*9+1], R2 = mrot[m*9+2];
    float R3 = mrot[m*9+3], R4 = mrot[m*9+4], R5 = mrot[m*9+5];
    float R6 = mrot[m*9+6], R7 = mrot[m*9+7], R8 = mrot[m*9+8];
    float posx = mpos[m*3+0], posy = mpos[m*3+1], posz = mpos[m*3+2];
    float sppx = spp[0], sppy = spp[1], sppz = spp[2];
    float spnx = spn[0], spny = spn[1], spnz = spn[2];

    float tpx = R0*px + R1*py + R2*pz + posx;
    float tpy = R3*px + R4*py + R5*pz + posy;
    float tpz = R6*px + R7*py + R8*pz + posz;
    float tnx = R0*nx + R1*ny + R2*nz;
    float tny = R3*nx + R4*ny + R5*nz;
    float tnz = R6*nx + R7*ny + R8*nz;

    float num = (sppx-tpx)*spnx + (sppy-tpy)*spny + (sppz-tpz)*spnz;

    int linb = blockIdx.x + (int)gridDim.x * (blockIdx.y + (int)gridDim.y * blockIdx.z);
    float* __restrict__ img = imgs + (size_t)(linb % K) * NPIX;

    for (int j = 0; j < SPT; j++) {
        const int s = s0 + j;
        float sx = sources[s*3+0], sy = sources[s*3+1], sz = sources[s*3+2];

        float dx = tpx - sx, dy = tpy - sy, dz = tpz - sz;
        float il = frsq(dx*dx + dy*dy + dz*dz);
        dx *= il; dy *= il; dz *= il;
        float ux = -dx, uy = -dy, uz = -dz;

        unsigned pm = masks[(unsigned)m * NS + (unsigned)s];
        pm = __builtin_amdgcn_readfirstlane(pm);
        unsigned cmask = pm & 0xFFFFu;
        unsigned bmask = (pm >> 16) & 0xFFu;

        bool hit = false;

        while (cmask) {
            int c = __builtin_ctz(cmask);
            cmask &= cmask - 1;
            float4 c0 = s_cyl[c][0];
            float4 c1 = s_cyl[c][1];
            float ocx = tpx - c0.x, ocy = tpy - c0.y, ocz = tpz - c0.z;
            float oa  = ocx*c1.x + ocy*c1.y + ocz*c1.z;
            float Cc  = ocx*ocx + ocy*ocy + ocz*ocz - oa*oa - c1.w;
            float ua  = ux*c1.x + uy*c1.y + uz*c1.z;
            float ocu = ux*ocx + uy*ocy + uz*ocz;
            float Bh  = fmaf(-oa, ua, ocu);
            float A   = fmaf(-ua, ua, 1.0f);
            float disc = fmaf(Bh, Bh, -(A*Cc));
            float sq   = fsqrt_(fmaxf(disc, 0.0f));
            float Ah   = A + 0.5f*FEPS;
            float q1   = -Bh - sq;
            float q2   = -Bh + sq;
            float oaA  = oa * Ah;
            float LA   = c0.w * Ah;
            float epsA = FEPS * Ah;
            float ax1A = fmaf(q1, ua, oaA);
            float ax2A = fmaf(q2, ua, oaA);
            bool dpos  = disc > 0.0f;
            hit = hit | (dpos & (q1 > epsA) & (ax1A >= 0.0f) & (ax1A <= LA))
                      | (dpos & (q2 > epsA) & (ax2A >= 0.0f) & (ax2A <= LA));
        }

        if (bmask) {
            float ivx = frcp((fabsf(ux) < FEPS) ? FEPS : ux);
            float ivy = frcp((fabsf(uy) < FEPS) ? FEPS : uy);
            float ivz = frcp((fabsf(uz) < FEPS) ? FEPS : uz);
            while (bmask) {
                int b = __builtin_ctz(bmask);
                bmask &= bmask - 1;
                float4 b1 = s_box[b][0];
                float4 b2 = s_box[b][1];
                float t0x = (b1.x - tpx) * ivx, t1x = (b2.x - tpx) * ivx;
                float t0y = (b1.y - tpy) * ivy, t1y = (b2.y - tpy) * ivy;
                float t0z = (b1.z - tpz) * ivz, t1z = (b2.z - tpz) * ivz;
                float tmin = fmaxf(fmaxf(fminf(t0x,t1x), fminf(t0y,t1y)), fminf(t0z,t1z));
                float tmax = fminf(fminf(fmaxf(t0x,t1x), fmaxf(t0y,t1y)), fmaxf(t0z,t1z));
                hit = hit | (tmax >= fmaxf(tmin, FEPS));
            }
        }

        {
            float dn = dx*tnx + dy*tny + dz*tnz;
            float rx = fmaf(-2.0f*dn, tnx, dx);
            float ry = fmaf(-2.0f*dn, tny, dy);
            float rz = fmaf(-2.0f*dn, tnz, dz);
            float cosv  = fabsf(dn);
            float denom = rx*spnx + ry*spny + rz*spnz;
            float tt = num * frcp(denom + FEPS);
            float qx = fmaf(tt, rx, tpx);
            float qy = fmaf(tt, ry, tpy);
            float fx = (qx + FEXT) * PXSCALE;
            float fy = (qy + FEXT) * PXSCALE;
            float fxf = floorf(fx), fyf = floorf(fy);
            bool inb = (fxf >= 0.0f) & (fxf < (float)IW) & (fyf >= 0.0f) & (fyf < (float)IH)
                       & (!hit);
            if (inb) atomicAdd(&img[(int)fyf * IW + (int)fxf], cosv);
        }
    }
}

__global__ __launch_bounds__(256) void reduce_kernel(
    const float* __restrict__ imgs, int K, float* __restrict__ out)
{
    int i = blockIdx.x * 256 + threadIdx.x;
    float v = 0.0f;
    for (int k = 0; k < K; k++) v += imgs[(size_t)k * NPIX + i];
    out[i] = v;
}

extern "C" void kernel_launch(void* const* d_in, const int* in_sizes, int n_in,
                              void* d_out, int out_size, void* d_ws, size_t ws_size,
                              hipStream_t stream) {
    const float* sources = (const float*)d_in[0];
    const float* mpts    = (const float*)d_in[1];
    const float* mnrm    = (const float*)d_in[2];
    const float* mpos    = (const float*)d_in[3];
    const float* mrot    = (const float*)d_in[4];
    const float* cp1     = (const float*)d_in[5];
    const float* cp2     = (const float*)d_in[6];
    const float* crad    = (const float*)d_in[7];
    const float* bp1     = (const float*)d_in[8];
    const float* bp2     = (const float*)d_in[9];
    const float* spp     = (const float*)d_in[10];
    const float* spn     = (const float*)d_in[11];

    const size_t CNT_BYTES = 4096;
    const size_t BND_BYTES = 1024;
    const size_t MSK_BYTES = (size_t)NM * NS * 4u;   // 32 KiB
    const size_t GIMG_BYTES = (size_t)MAXSPLIT * NPIX * 4u;   // 64 MiB

    // Adaptive tilecap (multiple of 4): prefer capacity.
    unsigned tilecap = 0;
    {
        const unsigned cap_opts[4] = {262144u, 196608u, 131072u, 65536u};
        for (int ci = 0; ci < 4; ci++) {
            size_t need = (size_t)NTILE * cap_opts[ci] * 4u + GIMG_BYTES
                        + CNT_BYTES + BND_BYTES + MSK_BYTES;
            if (need <= ws_size) { tilecap = cap_opts[ci]; break; }
        }
    }

    if (tilecap > 0) {
        // ---------- descriptor-free binning pipeline ----------
        char* p = (char*)d_ws;
        unsigned* arena     = (unsigned*)p;               p += (size_t)NTILE * tilecap * 4u;
        float*    gimg      = (float*)p;                  p += GIMG_BYTES;
        unsigned* tile_cnt  = (unsigned*)p;               // [0..255]
        unsigned* valid_end = tile_cnt + 256;             // [256..511]
        p += CNT_BYTES;
        float4*   bounds    = (float4*)p;                 p += BND_BYTES;
        unsigned* masks     = (unsigned*)p;

        hipMemsetAsync(tile_cnt, 0, 1024, stream);
        hipMemsetAsync(valid_end, 0xFF, 1024, stream);    // ~0u = no overflow
        hipMemsetAsync(d_out, 0, (size_t)NPIX * sizeof(float), stream);

        mirror_bounds_kernel<<<NM, 256, 0, stream>>>(mpts, mpos, mrot, bounds);
        mask_kernel<<<(NM * NS + 255) / 256, 256, 0, stream>>>(
            sources, cp1, cp2, crad, bp1, bp2, bounds, masks);

        dim3 grid(NP / 256, NS / SPT, NM);   // (8,16,64) = 8192 blocks
        render_bin_kernel<<<grid, 256, 0, stream>>>(
            sources, mpts, mnrm, mpos, mrot, cp1, cp2, crad, bp1, bp2, spp, spn,
            masks, arena, tile_cnt, valid_end, (float*)d_out, tilecap);

        dim3 grid2(NTILE, MAXSPLIT);         // idle splits exit with no stores
        tile_accum_kernel<<<grid2, 256, 0, stream>>>((const uint4*)arena, tile_cnt,
                                                     valid_end, tilecap, gimg);

        reduce_bin_kernel<<<(NPIX/4) / 256, 256, 0, stream>>>(
            (const float4*)gimg, tile_cnt, valid_end, tilecap, (float4*)d_out);
    } else {
        // ---------- R7 fallback: direct atomics with K privatized images ----------
        const size_t IMG_BYTES = (size_t)NPIX * sizeof(float);
        const size_t AUX_BYTES = 1024 + (size_t)NM * NS * sizeof(unsigned);
        int K = 0;
        for (int k = 8; k >= 1; k >>= 1) {
            if ((size_t)k * IMG_BYTES + AUX_BYTES <= ws_size) { K = k; break; }
        }
        float* imgs;
        char*  aux;
        if (K >= 1) {
            imgs = (float*)d_ws;
            aux  = (char*)d_ws + (size_t)K * IMG_BYTES;
            hipMemsetAsync(imgs, 0, (size_t)K * IMG_BYTES, stream);
        } else {
            K    = 1;
            imgs = (float*)d_out;
            aux  = (char*)d_ws;
            hipMemsetAsync(imgs, 0, IMG_BYTES, stream);
        }
        float4*   bounds = (float4*)aux;
        unsigned* masks  = (unsigned*)(aux + 1024);

        mirror_bounds_kernel<<<NM, 256, 0, stream>>>(mpts, mpos, mrot, bounds);
        mask_kernel<<<(NM * NS + 255) / 256, 256, 0, stream>>>(
            sources, cp1, cp2, crad, bp1, bp2, bounds, masks);

        dim3 grid(NP / 256, NS / SPT, NM);
        render_kernel<<<grid, 256, 0, stream>>>(sources, mpts, mnrm, mpos, mrot,
                                                cp1, cp2, crad, bp1, bp2, spp, spn,
                                                masks, imgs, K);
        if (imgs != (float*)d_out) {
            reduce_kernel<<<NPIX / 256, 256, 0, stream>>>(imgs, K, (float*)d_out);
        }
    }
}